// Round 1
// baseline (1000.042 us; speedup 1.0000x reference)
//
#include <hip/hip_runtime.h>

#define G 8                 // output points per workgroup
#define THREADS 512
#define NSLOTS (THREADS / 32)   // 16 edge slots
#define IN_CH 32
#define OUT_CH 64
#define KK 4
#define K3 64

__global__ __launch_bounds__(THREADS) void cconv_fused_kernel(
    const float* __restrict__ feats,        // [N_IN, 32]
    const float* __restrict__ inp_points,   // [N_IN, 3]
    const float* __restrict__ out_points,   // [N_OUT, 3]
    const float* __restrict__ out_extents,  // [1]
    const float* __restrict__ scale_compat, // [E]
    const int*   __restrict__ nbr_index,    // [E]
    const int*   __restrict__ row_splits,   // [N_OUT+1]
    const float* __restrict__ nbr_dist,     // [E]
    const float* __restrict__ Wmat,         // [64, 32, 64] (K3, IN, OUT)
    const float* __restrict__ bias,         // [64]
    float* __restrict__ out,                // [N_OUT, 64]
    int n_out)
{
    __shared__ float A_s[G * K3 * IN_CH];   // 64 KB accumulator
    __shared__ float den_s[G];
    __shared__ int   rs_s[G + 1];

    const int tid = threadIdx.x;
    const int g0  = blockIdx.x * G;

    // zero LDS accumulators
    for (int i = tid; i < G * K3 * IN_CH; i += THREADS) A_s[i] = 0.0f;
    if (tid < G) den_s[tid] = 0.0f;
    if (tid <= G) {
        int gg = g0 + tid;
        if (gg > n_out) gg = n_out;
        rs_s[tid] = row_splits[gg];
    }
    __syncthreads();

    const float inv_ext = 2.0f / out_extents[0];

    // hoist row splits into registers
    int rsl[G + 1];
    #pragma unroll
    for (int t = 0; t <= G; ++t) rsl[t] = rs_s[t];
    const int e0 = rsl[0];
    const int e1 = rsl[G];

    // ---------------- Phase A: edge scatter into LDS ----------------
    const int slot = tid >> 5;   // 0..15
    const int c    = tid & 31;   // channel lane

    for (int e = e0 + slot; e < e1; e += NSLOTS) {
        const int   nbr  = nbr_index[e];
        const float dist = nbr_dist[e];
        float p = 1.0f - dist * dist;
        p = p * p * p;
        p = fminf(fmaxf(p, 0.0f), 1.0f);
        const float imp = scale_compat[e] * p;

        // local row index: last t with rsl[t] <= e
        int g = 0;
        #pragma unroll
        for (int t = 1; t < G; ++t) g += (e >= rsl[t]) ? 1 : 0;

        const float rx = (inp_points[nbr * 3 + 0] - out_points[(g0 + g) * 3 + 0]) * inv_ext;
        const float ry = (inp_points[nbr * 3 + 1] - out_points[(g0 + g) * 3 + 1]) * inv_ext;
        const float rz = (inp_points[nbr * 3 + 2] - out_points[(g0 + g) * 3 + 2]) * inv_ext;

        const float r   = sqrtf(rx * rx + ry * ry + rz * rz);
        const float ax  = fabsf(rx), ay = fabsf(ry), az = fabsf(rz);
        const float inf = fmaxf(ax, fmaxf(ay, az));
        const float scl = (inf > 1e-8f) ? (r / fmaxf(inf, 1e-8f)) : 0.0f;

        const float ux = fminf(fmaxf(rx * scl, -1.0f), 1.0f);
        const float uy = fminf(fmaxf(ry * scl, -1.0f), 1.0f);
        const float uz = fminf(fmaxf(rz * scl, -1.0f), 1.0f);

        const float tx = (ux + 1.0f) * 1.5f;
        const float ty = (uy + 1.0f) * 1.5f;
        const float tz = (uz + 1.0f) * 1.5f;

        const float fx = fminf(fmaxf(floorf(tx), 0.0f), 2.0f);
        const float fy = fminf(fmaxf(floorf(ty), 0.0f), 2.0f);
        const float fz = fminf(fmaxf(floorf(tz), 0.0f), 2.0f);

        const float frx = tx - fx, fry = ty - fy, frz = tz - fz;
        const int ix = (int)fx, iy = (int)fy, iz = (int)fz;

        const float fwc = feats[nbr * IN_CH + c] * imp;

        const float wx0 = 1.0f - frx, wx1 = frx;
        const float wy0 = 1.0f - fry, wy1 = fry;
        const float wz0 = 1.0f - frz, wz1 = frz;

        float* Ab = &A_s[(g * K3) * IN_CH];
        const int base = (ix * KK + iy) * KK + iz;

        float w;
        w = wx0 * wy0 * wz0; if (w > 0.0f) atomicAdd(&Ab[(base     ) * IN_CH + c], fwc * w);
        w = wx0 * wy0 * wz1; if (w > 0.0f) atomicAdd(&Ab[(base +  1) * IN_CH + c], fwc * w);
        w = wx0 * wy1 * wz0; if (w > 0.0f) atomicAdd(&Ab[(base +  4) * IN_CH + c], fwc * w);
        w = wx0 * wy1 * wz1; if (w > 0.0f) atomicAdd(&Ab[(base +  5) * IN_CH + c], fwc * w);
        w = wx1 * wy0 * wz0; if (w > 0.0f) atomicAdd(&Ab[(base + 16) * IN_CH + c], fwc * w);
        w = wx1 * wy0 * wz1; if (w > 0.0f) atomicAdd(&Ab[(base + 17) * IN_CH + c], fwc * w);
        w = wx1 * wy1 * wz0; if (w > 0.0f) atomicAdd(&Ab[(base + 20) * IN_CH + c], fwc * w);
        w = wx1 * wy1 * wz1; if (w > 0.0f) atomicAdd(&Ab[(base + 21) * IN_CH + c], fwc * w);

        if (c == 0) atomicAdd(&den_s[g], imp);
    }
    __syncthreads();

    // ---------------- Phase B: y[g][o] = sum_{k,i} A[g][k][i] * W[k][i][o] ----
    const int o = tid & 63;      // output channel
    const int q = tid >> 6;      // 0..7, owns 8 kbins

    float acc[G];
    #pragma unroll
    for (int g = 0; g < G; ++g) acc[g] = 0.0f;

    for (int k = q * 8; k < q * 8 + 8; ++k) {
        const float* Wk = Wmat + (k * IN_CH) * OUT_CH + o;
        #pragma unroll
        for (int ib = 0; ib < IN_CH; ib += 4) {
            const float w0 = Wk[(ib + 0) * OUT_CH];
            const float w1 = Wk[(ib + 1) * OUT_CH];
            const float w2 = Wk[(ib + 2) * OUT_CH];
            const float w3 = Wk[(ib + 3) * OUT_CH];
            #pragma unroll
            for (int g = 0; g < G; ++g) {
                const float4 a = *(const float4*)&A_s[(g * K3 + k) * IN_CH + ib];
                acc[g] = fmaf(a.x, w0, acc[g]);
                acc[g] = fmaf(a.y, w1, acc[g]);
                acc[g] = fmaf(a.z, w2, acc[g]);
                acc[g] = fmaf(a.w, w3, acc[g]);
            }
        }
    }
    __syncthreads();

    // reduce across the 8 q-partials; reuse A_s as scratch [8q][8g][64o]
    float* red = A_s;
    #pragma unroll
    for (int g = 0; g < G; ++g) red[(q * G + g) * OUT_CH + o] = acc[g];
    __syncthreads();

    const int go = tid >> 6;     // 0..7 -> local g (requires G == 8)
    float s = 0.0f;
    #pragma unroll
    for (int qq = 0; qq < 8; ++qq) s += red[(qq * G + go) * OUT_CH + o];

    float d = den_s[go];
    d = (d != 0.0f) ? d : 1.0f;
    float y = s / d + bias[o];
    y = fmaxf(y, 0.0f);

    const int row = g0 + go;
    if (row < n_out) out[row * OUT_CH + o] = y;
}

extern "C" void kernel_launch(void* const* d_in, const int* in_sizes, int n_in,
                              void* d_out, int out_size, void* d_ws, size_t ws_size,
                              hipStream_t stream) {
    const float* feats        = (const float*)d_in[0];
    const float* inp_points   = (const float*)d_in[1];
    const float* out_points   = (const float*)d_in[2];
    const float* out_extents  = (const float*)d_in[3];
    const float* scale_compat = (const float*)d_in[4];
    const int*   nbr_index    = (const int*)d_in[5];
    const int*   row_splits   = (const int*)d_in[6];
    const float* nbr_dist     = (const float*)d_in[7];
    const float* Wmat         = (const float*)d_in[8];
    const float* bias         = (const float*)d_in[9];
    float*       out          = (float*)d_out;

    const int n_out = in_sizes[2] / 3;
    if (n_out <= 0) return;
    const int nwg = (n_out + G - 1) / G;

    hipLaunchKernelGGL(cconv_fused_kernel, dim3(nwg), dim3(THREADS), 0, stream,
                       feats, inp_points, out_points, out_extents, scale_compat,
                       nbr_index, row_splits, nbr_dist, Wmat, bias, out, n_out);
}

// Round 2
// 886.881 us; speedup vs baseline: 1.1276x; 1.1276x over previous
//
#include <hip/hip_runtime.h>

#define G 8                 // output points per workgroup
#define THREADS 512
#define NSLOTS (THREADS / 32)   // 16 edge slots
#define IN_CH 32
#define OUT_CH 64
#define KK 4
#define K3 64

// A storage swizzle: element (g,k,c) lives at float index
//   (g*64+k)*32 + (c ^ ((k&7)<<2))
// XOR on bits 2..4 spreads the 16B slot of each k-row across banks so
// Phase-B's 4-distinct-address broadcast reads are conflict-free, and
// Phase-A's per-lane c=0..31 writes stay a full bank permutation.

__global__ __launch_bounds__(THREADS) void cconv_fused_kernel(
    const float* __restrict__ feats,        // [N_IN, 32]
    const float* __restrict__ inp_points,   // [N_IN, 3]
    const float* __restrict__ out_points,   // [N_OUT, 3]
    const float* __restrict__ out_extents,  // [1]
    const float* __restrict__ scale_compat, // [E]
    const int*   __restrict__ nbr_index,    // [E]
    const int*   __restrict__ row_splits,   // [N_OUT+1]
    const float* __restrict__ nbr_dist,     // [E]
    const float* __restrict__ Wmat,         // [64, 32, 64] (K3, IN, OUT)
    const float* __restrict__ bias,         // [64]
    float* __restrict__ out,                // [N_OUT, 64]
    int n_out)
{
    __shared__ float A_s[G * K3 * IN_CH];   // 64 KB accumulator / reduce scratch
    __shared__ float den_s[G];
    __shared__ int   rs_s[G + 1];
    __shared__ float opts_s[G * 3];

    const int tid = threadIdx.x;
    const int g0  = blockIdx.x * G;

    // zero LDS accumulators
    for (int i = tid; i < G * K3 * IN_CH; i += THREADS) A_s[i] = 0.0f;
    if (tid < G) den_s[tid] = 0.0f;
    if (tid <= G) {
        int gg = g0 + tid;
        if (gg > n_out) gg = n_out;
        rs_s[tid] = row_splits[gg];
    }
    if (tid < G * 3) {
        int gg = g0 + tid / 3;
        opts_s[tid] = (gg < n_out) ? out_points[gg * 3 + tid % 3] : 0.0f;
    }
    __syncthreads();

    const float inv_ext = 2.0f / out_extents[0];

    int rsl[G + 1];
    #pragma unroll
    for (int t = 0; t <= G; ++t) rsl[t] = rs_s[t];
    const int e0 = rsl[0];
    const int e1 = rsl[G];

    // ---------------- Phase A: edge scatter into LDS ----------------
    const int slot = tid >> 5;   // 0..15
    const int c    = tid & 31;   // channel lane

    for (int e = e0 + slot; e < e1; e += NSLOTS) {
        const int   nbr  = nbr_index[e];
        const float dist = nbr_dist[e];
        float p = 1.0f - dist * dist;
        p = p * p * p;
        p = fminf(fmaxf(p, 0.0f), 1.0f);
        const float imp = scale_compat[e] * p;

        int g = 0;
        #pragma unroll
        for (int t = 1; t < G; ++t) g += (e >= rsl[t]) ? 1 : 0;

        const float rx = (inp_points[nbr * 3 + 0] - opts_s[g * 3 + 0]) * inv_ext;
        const float ry = (inp_points[nbr * 3 + 1] - opts_s[g * 3 + 1]) * inv_ext;
        const float rz = (inp_points[nbr * 3 + 2] - opts_s[g * 3 + 2]) * inv_ext;

        const float r   = sqrtf(rx * rx + ry * ry + rz * rz);
        const float ax  = fabsf(rx), ay = fabsf(ry), az = fabsf(rz);
        const float inf = fmaxf(ax, fmaxf(ay, az));
        const float scl = (inf > 1e-8f) ? (r / fmaxf(inf, 1e-8f)) : 0.0f;

        const float ux = fminf(fmaxf(rx * scl, -1.0f), 1.0f);
        const float uy = fminf(fmaxf(ry * scl, -1.0f), 1.0f);
        const float uz = fminf(fmaxf(rz * scl, -1.0f), 1.0f);

        const float tx = (ux + 1.0f) * 1.5f;
        const float ty = (uy + 1.0f) * 1.5f;
        const float tz = (uz + 1.0f) * 1.5f;

        const float fx = fminf(fmaxf(floorf(tx), 0.0f), 2.0f);
        const float fy = fminf(fmaxf(floorf(ty), 0.0f), 2.0f);
        const float fz = fminf(fmaxf(floorf(tz), 0.0f), 2.0f);

        const float frx = tx - fx, fry = ty - fy, frz = tz - fz;
        const int ix = (int)fx, iy = (int)fy, iz = (int)fz;

        const float fwc = feats[nbr * IN_CH + c] * imp;

        const float wx0 = 1.0f - frx, wx1 = frx;
        const float wy0 = 1.0f - fry, wy1 = fry;
        const float wz0 = 1.0f - frz, wz1 = frz;

        const int gb   = g << 6;                 // g*64
        const int base = (ix * KK + iy) * KK + iz;

        float w; int k;
        #define SCATTER(OFF, WVAL)                                          \
            w = (WVAL); k = base + (OFF);                                   \
            if (w > 0.0f)                                                   \
                atomicAdd(&A_s[((gb + k) << 5) + (c ^ ((k & 7) << 2))], fwc * w);
        SCATTER(0,  wx0 * wy0 * wz0)
        SCATTER(1,  wx0 * wy0 * wz1)
        SCATTER(4,  wx0 * wy1 * wz0)
        SCATTER(5,  wx0 * wy1 * wz1)
        SCATTER(16, wx1 * wy0 * wz0)
        SCATTER(17, wx1 * wy0 * wz1)
        SCATTER(20, wx1 * wy1 * wz0)
        SCATTER(21, wx1 * wy1 * wz1)
        #undef SCATTER

        if (c == 0) atomicAdd(&den_s[g], imp);
    }
    __syncthreads();

    // ------- Phase B: y[g][o] = sum_{k,i} A[g][k][i] * W[k][i][o] -------
    // thread = (o_lo = tid&15 -> o = o_lo*4+j, j=0..3) x (q = tid>>4 -> k = 2q, 2q+1)
    const int o_lo = tid & 15;
    const int q    = tid >> 4;            // 0..31

    float4 acc[G];
    #pragma unroll
    for (int g = 0; g < G; ++g) acc[g] = make_float4(0.f, 0.f, 0.f, 0.f);

    const float4* __restrict__ A4 = (const float4*)A_s;
    const float4* __restrict__ W4 = (const float4*)Wmat;

    #pragma unroll
    for (int kk = 0; kk < 2; ++kk) {
        const int k   = q * 2 + kk;
        const int swz = k & 7;
        #pragma unroll
        for (int ib = 0; ib < 8; ++ib) {
            const int wbase = (k * IN_CH + ib * 4) * 16 + o_lo;
            const float4 w0 = W4[wbase];
            const float4 w1 = W4[wbase + 16];
            const float4 w2 = W4[wbase + 32];
            const float4 w3 = W4[wbase + 48];
            #pragma unroll
            for (int g = 0; g < G; ++g) {
                const float4 a = A4[((g << 6) + k) * 8 + (ib ^ swz)];
                acc[g].x = fmaf(a.x, w0.x, acc[g].x);
                acc[g].y = fmaf(a.x, w0.y, acc[g].y);
                acc[g].z = fmaf(a.x, w0.z, acc[g].z);
                acc[g].w = fmaf(a.x, w0.w, acc[g].w);
                acc[g].x = fmaf(a.y, w1.x, acc[g].x);
                acc[g].y = fmaf(a.y, w1.y, acc[g].y);
                acc[g].z = fmaf(a.y, w1.z, acc[g].z);
                acc[g].w = fmaf(a.y, w1.w, acc[g].w);
                acc[g].x = fmaf(a.z, w2.x, acc[g].x);
                acc[g].y = fmaf(a.z, w2.y, acc[g].y);
                acc[g].z = fmaf(a.z, w2.z, acc[g].z);
                acc[g].w = fmaf(a.z, w2.w, acc[g].w);
                acc[g].x = fmaf(a.w, w3.x, acc[g].x);
                acc[g].y = fmaf(a.w, w3.y, acc[g].y);
                acc[g].z = fmaf(a.w, w3.z, acc[g].z);
                acc[g].w = fmaf(a.w, w3.w, acc[g].w);
            }
        }
    }
    __syncthreads();   // all A_s reads done; safe to overwrite as scratch

    // stage partials: A_s reused as red[32 q][512 outputs]
    float4* red4 = (float4*)A_s;
    #pragma unroll
    for (int g = 0; g < G; ++g) red4[q * 128 + g * 16 + o_lo] = acc[g];
    __syncthreads();

    const int go = tid >> 6;     // 0..7  (requires G == 8)
    const int o  = tid & 63;
    const float* red = A_s;
    float s = 0.0f;
    #pragma unroll
    for (int qq = 0; qq < 32; ++qq) s += red[qq * 512 + go * 64 + o];

    float d = den_s[go];
    d = (d != 0.0f) ? d : 1.0f;
    float y = s / d + bias[o];
    y = fmaxf(y, 0.0f);

    const int row = g0 + go;
    if (row < n_out) out[row * OUT_CH + o] = y;
}

extern "C" void kernel_launch(void* const* d_in, const int* in_sizes, int n_in,
                              void* d_out, int out_size, void* d_ws, size_t ws_size,
                              hipStream_t stream) {
    const float* feats        = (const float*)d_in[0];
    const float* inp_points   = (const float*)d_in[1];
    const float* out_points   = (const float*)d_in[2];
    const float* out_extents  = (const float*)d_in[3];
    const float* scale_compat = (const float*)d_in[4];
    const int*   nbr_index    = (const int*)d_in[5];
    const int*   row_splits   = (const int*)d_in[6];
    const float* nbr_dist     = (const float*)d_in[7];
    const float* Wmat         = (const float*)d_in[8];
    const float* bias         = (const float*)d_in[9];
    float*       out          = (float*)d_out;

    const int n_out = in_sizes[2] / 3;
    if (n_out <= 0) return;
    const int nwg = (n_out + G - 1) / G;

    hipLaunchKernelGGL(cconv_fused_kernel, dim3(nwg), dim3(THREADS), 0, stream,
                       feats, inp_points, out_points, out_extents, scale_compat,
                       nbr_index, row_splits, nbr_dist, Wmat, bias, out, n_out);
}

// Round 3
// 672.261 us; speedup vs baseline: 1.4876x; 1.3193x over previous
//
#include <hip/hip_runtime.h>

#define G 8                 // output points per workgroup (1 wave per point in Phase B)
#define THREADS 512
#define NSLOTS (THREADS / 32)   // 16 edge slots
#define IN_CH 32
#define OUT_CH 64
#define KK 4
#define K3 64

__global__ __launch_bounds__(THREADS) void cconv_fused_kernel(
    const float* __restrict__ feats,        // [N_IN, 32]
    const float* __restrict__ inp_points,   // [N_IN, 3]
    const float* __restrict__ out_points,   // [N_OUT, 3]
    const float* __restrict__ out_extents,  // [1]
    const float* __restrict__ scale_compat, // [E]
    const int*   __restrict__ nbr_index,    // [E]
    const int*   __restrict__ row_splits,   // [N_OUT+1]
    const float* __restrict__ nbr_dist,     // [E]
    const float* __restrict__ Wmat,         // [64, 32, 64] (K3, IN, OUT)
    const float* __restrict__ bias,         // [64]
    float* __restrict__ out,                // [N_OUT, 64]
    int n_out)
{
    __shared__ float A_s[G * K3 * IN_CH];        // 64 KB accumulator
    __shared__ float den_s[G];
    __shared__ unsigned int mask_s[G][2];        // per-point k-bin occupancy bits
    __shared__ int   rs_s[G + 1];
    __shared__ float opts_s[G * 3];

    const int tid = threadIdx.x;
    const int g0  = blockIdx.x * G;

    // zero LDS accumulator (vectorized: 4096 float4 / 512 threads = 8 each)
    {
        float4* A4z = (float4*)A_s;
        #pragma unroll
        for (int i = 0; i < 8; ++i)
            A4z[tid + i * THREADS] = make_float4(0.f, 0.f, 0.f, 0.f);
    }
    if (tid < G) { den_s[tid] = 0.0f; mask_s[tid][0] = 0u; mask_s[tid][1] = 0u; }
    if (tid <= G) {
        int gg = g0 + tid;
        if (gg > n_out) gg = n_out;
        rs_s[tid] = row_splits[gg];
    }
    if (tid < G * 3) {
        int gg = g0 + tid / 3;
        opts_s[tid] = (gg < n_out) ? out_points[gg * 3 + tid % 3] : 0.0f;
    }
    __syncthreads();

    const float inv_ext = 2.0f / out_extents[0];

    int rsl[G + 1];
    #pragma unroll
    for (int t = 0; t <= G; ++t) rsl[t] = rs_s[t];
    const int e1 = rsl[G];

    // ---------------- Phase A: edge scatter into LDS ----------------
    const int slot = tid >> 5;   // 0..15
    const int c    = tid & 31;   // channel lane

    int e = rsl[0] + slot;
    // 2-stage software pipeline on the edge-stream + neighbor-dependent loads
    int   nbr  = 0;
    float sc   = 0.f, dist = 0.f, px = 0.f, py = 0.f, pz = 0.f, fv = 0.f;
    if (e < e1) {
        nbr  = nbr_index[e];
        sc   = scale_compat[e];
        dist = nbr_dist[e];
        px   = inp_points[nbr * 3 + 0];
        py   = inp_points[nbr * 3 + 1];
        pz   = inp_points[nbr * 3 + 2];
        fv   = feats[nbr * IN_CH + c];
    }

    while (e < e1) {
        const int   cur_e = e;
        const float c_sc = sc, c_d = dist, c_px = px, c_py = py, c_pz = pz, c_fv = fv;

        const int en = e + NSLOTS;
        if (en < e1) {
            const int n2 = nbr_index[en];
            nbr  = n2;
            sc   = scale_compat[en];
            dist = nbr_dist[en];
            px   = inp_points[n2 * 3 + 0];
            py   = inp_points[n2 * 3 + 1];
            pz   = inp_points[n2 * 3 + 2];
            fv   = feats[n2 * IN_CH + c];
        }
        e = en;

        float p = 1.0f - c_d * c_d;
        p = p * p * p;
        p = fminf(fmaxf(p, 0.0f), 1.0f);
        const float imp = c_sc * p;

        int g = 0;
        #pragma unroll
        for (int t = 1; t < G; ++t) g += (cur_e >= rsl[t]) ? 1 : 0;

        const float rx = (c_px - opts_s[g * 3 + 0]) * inv_ext;
        const float ry = (c_py - opts_s[g * 3 + 1]) * inv_ext;
        const float rz = (c_pz - opts_s[g * 3 + 2]) * inv_ext;

        const float r   = sqrtf(rx * rx + ry * ry + rz * rz);
        const float ax  = fabsf(rx), ay = fabsf(ry), az = fabsf(rz);
        const float inf = fmaxf(ax, fmaxf(ay, az));
        const float scl = (inf > 1e-8f) ? (r / fmaxf(inf, 1e-8f)) : 0.0f;

        const float ux = fminf(fmaxf(rx * scl, -1.0f), 1.0f);
        const float uy = fminf(fmaxf(ry * scl, -1.0f), 1.0f);
        const float uz = fminf(fmaxf(rz * scl, -1.0f), 1.0f);

        const float tx = (ux + 1.0f) * 1.5f;
        const float ty = (uy + 1.0f) * 1.5f;
        const float tz = (uz + 1.0f) * 1.5f;

        const float fx = fminf(fmaxf(floorf(tx), 0.0f), 2.0f);
        const float fy = fminf(fmaxf(floorf(ty), 0.0f), 2.0f);
        const float fz = fminf(fmaxf(floorf(tz), 0.0f), 2.0f);

        const float frx = tx - fx, fry = ty - fy, frz = tz - fz;
        const int ix = (int)fx, iy = (int)fy, iz = (int)fz;

        const float fwc = c_fv * imp;

        const float wx0 = 1.0f - frx, wx1 = frx;
        const float wy0 = 1.0f - fry, wy1 = fry;
        const float wz0 = 1.0f - frz, wz1 = frz;

        const int gb   = g << 6;                 // g*64
        const int base = (ix * KK + iy) * KK + iz;

        unsigned int em_lo = 0u, em_hi = 0u;
        float w; int k;
        #define SCATTER(OFF, WVAL)                                          \
            w = (WVAL); k = base + (OFF);                                   \
            if (w > 0.0f) {                                                 \
                atomicAdd(&A_s[((gb + k) << 5) + c], fwc * w);              \
                if (k < 32) em_lo |= (1u << k); else em_hi |= (1u << (k - 32)); \
            }
        SCATTER(0,  wx0 * wy0 * wz0)
        SCATTER(1,  wx0 * wy0 * wz1)
        SCATTER(4,  wx0 * wy1 * wz0)
        SCATTER(5,  wx0 * wy1 * wz1)
        SCATTER(16, wx1 * wy0 * wz0)
        SCATTER(17, wx1 * wy0 * wz1)
        SCATTER(20, wx1 * wy1 * wz0)
        SCATTER(21, wx1 * wy1 * wz1)
        #undef SCATTER

        if (c == 0) {
            atomicAdd(&den_s[g], imp);
            if (em_lo) atomicOr(&mask_s[g][0], em_lo);
            if (em_hi) atomicOr(&mask_s[g][1], em_hi);
        }
    }
    __syncthreads();

    // ------- Phase B (sparse): y[g][o] = sum_{k in mask} A[g][k][:] . W[k][:][o]
    // one wave per output point; lane = (o4 = lane&15 -> o quad, i4 = lane>>4 -> i octet)
    const int wave = tid >> 6;   // g (requires G == 8, THREADS == 512)
    const int lane = tid & 63;
    const int o4   = lane & 15;
    const int i4   = lane >> 4;

    unsigned long long m = ((unsigned long long)mask_s[wave][1] << 32) | mask_s[wave][0];

    float4 acc0 = make_float4(0.f, 0.f, 0.f, 0.f);
    float4 acc1 = make_float4(0.f, 0.f, 0.f, 0.f);
    float4 acc2 = make_float4(0.f, 0.f, 0.f, 0.f);
    float4 acc3 = make_float4(0.f, 0.f, 0.f, 0.f);

    const float4* __restrict__ W4 = (const float4*)Wmat;
    const float*  __restrict__ Ag = &A_s[(wave * K3) * IN_CH];

    while (m) {
        const int k = __ffsll(m) - 1;
        m &= (m - 1);

        const float4 a0 = *(const float4*)&Ag[(k << 5) + (i4 << 3)];
        const float4 a1 = *(const float4*)&Ag[(k << 5) + (i4 << 3) + 4];
        const float4* Wk = &W4[((k << 5) + (i4 << 3)) * 16 + o4];

        const float4 w0 = Wk[0];
        const float4 w1 = Wk[16];
        const float4 w2 = Wk[32];
        const float4 w3 = Wk[48];
        const float4 w4 = Wk[64];
        const float4 w5 = Wk[80];
        const float4 w6 = Wk[96];
        const float4 w7 = Wk[112];

        acc0.x = fmaf(a0.x, w0.x, acc0.x); acc0.y = fmaf(a0.x, w0.y, acc0.y);
        acc0.z = fmaf(a0.x, w0.z, acc0.z); acc0.w = fmaf(a0.x, w0.w, acc0.w);
        acc1.x = fmaf(a0.y, w1.x, acc1.x); acc1.y = fmaf(a0.y, w1.y, acc1.y);
        acc1.z = fmaf(a0.y, w1.z, acc1.z); acc1.w = fmaf(a0.y, w1.w, acc1.w);
        acc2.x = fmaf(a0.z, w2.x, acc2.x); acc2.y = fmaf(a0.z, w2.y, acc2.y);
        acc2.z = fmaf(a0.z, w2.z, acc2.z); acc2.w = fmaf(a0.z, w2.w, acc2.w);
        acc3.x = fmaf(a0.w, w3.x, acc3.x); acc3.y = fmaf(a0.w, w3.y, acc3.y);
        acc3.z = fmaf(a0.w, w3.z, acc3.z); acc3.w = fmaf(a0.w, w3.w, acc3.w);
        acc0.x = fmaf(a1.x, w4.x, acc0.x); acc0.y = fmaf(a1.x, w4.y, acc0.y);
        acc0.z = fmaf(a1.x, w4.z, acc0.z); acc0.w = fmaf(a1.x, w4.w, acc0.w);
        acc1.x = fmaf(a1.y, w5.x, acc1.x); acc1.y = fmaf(a1.y, w5.y, acc1.y);
        acc1.z = fmaf(a1.y, w5.z, acc1.z); acc1.w = fmaf(a1.y, w5.w, acc1.w);
        acc2.x = fmaf(a1.z, w6.x, acc2.x); acc2.y = fmaf(a1.z, w6.y, acc2.y);
        acc2.z = fmaf(a1.z, w6.z, acc2.z); acc2.w = fmaf(a1.z, w6.w, acc2.w);
        acc3.x = fmaf(a1.w, w7.x, acc3.x); acc3.y = fmaf(a1.w, w7.y, acc3.y);
        acc3.z = fmaf(a1.w, w7.z, acc3.z); acc3.w = fmaf(a1.w, w7.w, acc3.w);
    }

    float4 t;
    t.x = (acc0.x + acc1.x) + (acc2.x + acc3.x);
    t.y = (acc0.y + acc1.y) + (acc2.y + acc3.y);
    t.z = (acc0.z + acc1.z) + (acc2.z + acc3.z);
    t.w = (acc0.w + acc1.w) + (acc2.w + acc3.w);

    // reduce across the 4 i4 groups (lanes l, l^16, l^32, l^48)
    t.x += __shfl_xor(t.x, 16); t.y += __shfl_xor(t.y, 16);
    t.z += __shfl_xor(t.z, 16); t.w += __shfl_xor(t.w, 16);
    t.x += __shfl_xor(t.x, 32); t.y += __shfl_xor(t.y, 32);
    t.z += __shfl_xor(t.z, 32); t.w += __shfl_xor(t.w, 32);

    const int row = g0 + wave;
    if (lane < 16 && row < n_out) {
        float d = den_s[wave];
        d = (d != 0.0f) ? d : 1.0f;
        const float inv_d = 1.0f / d;
        const float4 b4 = ((const float4*)bias)[o4];
        float4 y;
        y.x = fmaxf(t.x * inv_d + b4.x, 0.0f);
        y.y = fmaxf(t.y * inv_d + b4.y, 0.0f);
        y.z = fmaxf(t.z * inv_d + b4.z, 0.0f);
        y.w = fmaxf(t.w * inv_d + b4.w, 0.0f);
        ((float4*)out)[row * 16 + o4] = y;
    }
}

extern "C" void kernel_launch(void* const* d_in, const int* in_sizes, int n_in,
                              void* d_out, int out_size, void* d_ws, size_t ws_size,
                              hipStream_t stream) {
    const float* feats        = (const float*)d_in[0];
    const float* inp_points   = (const float*)d_in[1];
    const float* out_points   = (const float*)d_in[2];
    const float* out_extents  = (const float*)d_in[3];
    const float* scale_compat = (const float*)d_in[4];
    const int*   nbr_index    = (const int*)d_in[5];
    const int*   row_splits   = (const int*)d_in[6];
    const float* nbr_dist     = (const float*)d_in[7];
    const float* Wmat         = (const float*)d_in[8];
    const float* bias         = (const float*)d_in[9];
    float*       out          = (float*)d_out;

    const int n_out = in_sizes[2] / 3;
    if (n_out <= 0) return;
    const int nwg = (n_out + G - 1) / G;

    hipLaunchKernelGGL(cconv_fused_kernel, dim3(nwg), dim3(THREADS), 0, stream,
                       feats, inp_points, out_points, out_extents, scale_compat,
                       nbr_index, row_splits, nbr_dist, Wmat, bias, out, n_out);
}

// Round 5
// 668.971 us; speedup vs baseline: 1.4949x; 1.0049x over previous
//
#include <hip/hip_runtime.h>

#define G 8                 // output points per workgroup
#define THREADS 512
#define IN_CH 32
#define OUT_CH 64
#define KK 4
#define K3 64
#define CHUNK 256           // edges staged per A1/A2 round

__global__ __launch_bounds__(THREADS, 4) void cconv_fused_kernel(
    const float* __restrict__ feats,        // [N_IN, 32]
    const float* __restrict__ inp_points,   // [N_IN, 3]
    const float* __restrict__ out_points,   // [N_OUT, 3]
    const float* __restrict__ out_extents,  // [1]
    const float* __restrict__ scale_compat, // [E]
    const int*   __restrict__ nbr_index,    // [E]
    const int*   __restrict__ row_splits,   // [N_OUT+1]
    const float* __restrict__ nbr_dist,     // [E]
    const float* __restrict__ Wmat,         // [64, 32, 64] (K3, IN, OUT)
    const float* __restrict__ bias,         // [64]
    float* __restrict__ out,                // [N_OUT, 64]
    int n_out)
{
    __shared__ float A_s[G * K3 * IN_CH];        // 64 KB accumulator
    __shared__ float den_s[G];
    __shared__ unsigned int mask_s[G][2];
    __shared__ int   rs_s[G + 1];
    __shared__ float opts_s[G * 3];
    // staged per-edge records (SoA), 6 KB
    __shared__ int   st_nbr[CHUNK];
    __shared__ float st_imp[CHUNK];
    __shared__ float st_frx[CHUNK];
    __shared__ float st_fry[CHUNK];
    __shared__ float st_frz[CHUNK];
    __shared__ int   st_bg[CHUNK];               // base | (g<<8)

    const int tid  = threadIdx.x;
    const int g0   = blockIdx.x * G;
    const int lane = tid & 63;

    // zero LDS accumulator (4096 float4 / 512 threads = 8 each)
    {
        float4* A4z = (float4*)A_s;
        #pragma unroll
        for (int i = 0; i < 8; ++i)
            A4z[tid + i * THREADS] = make_float4(0.f, 0.f, 0.f, 0.f);
    }
    if (tid < G) { den_s[tid] = 0.f; mask_s[tid][0] = 0u; mask_s[tid][1] = 0u; }
    if (tid <= G) {
        int gg = g0 + tid;
        if (gg > n_out) gg = n_out;
        rs_s[tid] = row_splits[gg];
    }
    if (tid < G * 3) {
        int gg = g0 + tid / 3;
        opts_s[tid] = (gg < n_out) ? out_points[gg * 3 + tid % 3] : 0.f;
    }
    __syncthreads();

    const float inv_ext = 2.0f / out_extents[0];
    int rsl[G + 1];
    #pragma unroll
    for (int t = 0; t <= G; ++t) rsl[t] = rs_s[t];
    const int e0 = rsl[0], e1 = rsl[G];

    const int slot = tid >> 5;   // 0..15
    const int c    = tid & 31;   // channel lane

    for (int ch0 = e0; ch0 < e1; ch0 += CHUNK) {
        const int rem = e1 - ch0;
        const int nch = rem < CHUNK ? rem : CHUNK;

        // ---------- A1: one thread per edge, geometry once ----------
        int          eg   = -1;
        float        eimp = 0.f;
        unsigned int em_lo = 0u, em_hi = 0u;
        if (tid < nch) {
            const int   e   = ch0 + tid;
            const int   nbr = nbr_index[e];
            const float sc  = scale_compat[e];
            const float dd  = nbr_dist[e];
            float p = 1.f - dd * dd;
            p = p * p * p;
            p = fminf(fmaxf(p, 0.f), 1.f);
            const float imp = sc * p;

            int g = 0;
            #pragma unroll
            for (int t = 1; t < G; ++t) g += (e >= rsl[t]) ? 1 : 0;

            const float rx = (inp_points[nbr * 3 + 0] - opts_s[g * 3 + 0]) * inv_ext;
            const float ry = (inp_points[nbr * 3 + 1] - opts_s[g * 3 + 1]) * inv_ext;
            const float rz = (inp_points[nbr * 3 + 2] - opts_s[g * 3 + 2]) * inv_ext;

            const float r   = sqrtf(rx * rx + ry * ry + rz * rz);
            const float inf = fmaxf(fabsf(rx), fmaxf(fabsf(ry), fabsf(rz)));
            const float scl = (inf > 1e-8f) ? (r / fmaxf(inf, 1e-8f)) : 0.f;

            const float ux = fminf(fmaxf(rx * scl, -1.f), 1.f);
            const float uy = fminf(fmaxf(ry * scl, -1.f), 1.f);
            const float uz = fminf(fmaxf(rz * scl, -1.f), 1.f);

            const float tx = (ux + 1.f) * 1.5f;
            const float ty = (uy + 1.f) * 1.5f;
            const float tz = (uz + 1.f) * 1.5f;

            const float fx = fminf(fmaxf(floorf(tx), 0.f), 2.f);
            const float fy = fminf(fmaxf(floorf(ty), 0.f), 2.f);
            const float fz = fminf(fmaxf(floorf(tz), 0.f), 2.f);

            const float frx = tx - fx, fry = ty - fy, frz = tz - fz;
            const int ix = (int)fx, iy = (int)fy, iz = (int)fz;
            const int base = (ix * KK + iy) * KK + iz;

            st_nbr[tid] = nbr;
            st_imp[tid] = imp;
            st_frx[tid] = frx;
            st_fry[tid] = fry;
            st_frz[tid] = frz;
            st_bg[tid]  = base | (g << 8);

            const float wx0 = 1.f - frx, wx1 = frx;
            const float wy0 = 1.f - fry, wy1 = fry;
            const float wz0 = 1.f - frz, wz1 = frz;
            #define MB(OFF, WV) { if ((WV) > 0.f) { const int k = base + (OFF); \
                if (k < 32) em_lo |= (1u << k); else em_hi |= (1u << (k - 32)); } }
            MB(0,  wx0 * wy0 * wz0) MB(1,  wx0 * wy0 * wz1)
            MB(4,  wx0 * wy1 * wz0) MB(5,  wx0 * wy1 * wz1)
            MB(16, wx1 * wy0 * wz0) MB(17, wx1 * wy0 * wz1)
            MB(20, wx1 * wy1 * wz0) MB(21, wx1 * wy1 * wz1)
            #undef MB
            eg = g; eimp = imp;
        }
        if (tid < CHUNK) {
            // segmented inclusive scan over the wave (edges g-sorted; idle lanes g=-1)
            #pragma unroll
            for (int d = 1; d < 64; d <<= 1) {
                const float        oi = __shfl_up(eimp, d);
                const unsigned int ol = __shfl_up(em_lo, d);
                const unsigned int oh = __shfl_up(em_hi, d);
                const int          og = __shfl_up(eg, d);
                if (lane >= d && og == eg) { eimp += oi; em_lo |= ol; em_hi |= oh; }
            }
            const int gnext = __shfl_down(eg, 1);
            const bool tail = (lane == 63) || (gnext != eg);
            if (tail && eg >= 0) {
                atomicAdd(&den_s[eg], eimp);
                if (em_lo) atomicOr(&mask_s[eg][0], em_lo);
                if (em_hi) atomicOr(&mask_s[eg][1], em_hi);
            }
        }
        __syncthreads();

        // ---------- A2: scatter with 4-deep feats prefetch ----------
        #define SCAT(I, FV) { const int i = (I); if (i < nch) {               \
            const float imp = st_imp[i];                                      \
            const float frx = st_frx[i], fry = st_fry[i], frz = st_frz[i];    \
            const int bg = st_bg[i];                                          \
            const int g = bg >> 8; const int base = bg & 0xff;                \
            const float fwc = (FV) * imp;                                     \
            const float wx0 = 1.f - frx, wx1 = frx;                           \
            const float wy0 = 1.f - fry, wy1 = fry;                           \
            const float wz0 = 1.f - frz, wz1 = frz;                           \
            float* Ab = &A_s[(((g << 6) + base) << 5) + c]; float w;          \
            w = wx0 * wy0 * wz0; if (w > 0.f) atomicAdd(Ab + (0  << 5), fwc * w); \
            w = wx0 * wy0 * wz1; if (w > 0.f) atomicAdd(Ab + (1  << 5), fwc * w); \
            w = wx0 * wy1 * wz0; if (w > 0.f) atomicAdd(Ab + (4  << 5), fwc * w); \
            w = wx0 * wy1 * wz1; if (w > 0.f) atomicAdd(Ab + (5  << 5), fwc * w); \
            w = wx1 * wy0 * wz0; if (w > 0.f) atomicAdd(Ab + (16 << 5), fwc * w); \
            w = wx1 * wy0 * wz1; if (w > 0.f) atomicAdd(Ab + (17 << 5), fwc * w); \
            w = wx1 * wy1 * wz0; if (w > 0.f) atomicAdd(Ab + (20 << 5), fwc * w); \
            w = wx1 * wy1 * wz1; if (w > 0.f) atomicAdd(Ab + (21 << 5), fwc * w); } }

        float fv0, fv1, fv2, fv3;
        {
            const int i0 = slot, i1 = slot + 16, i2 = slot + 32, i3 = slot + 48;
            fv0 = (i0 < nch) ? feats[st_nbr[i0] * IN_CH + c] : 0.f;
            fv1 = (i1 < nch) ? feats[st_nbr[i1] * IN_CH + c] : 0.f;
            fv2 = (i2 < nch) ? feats[st_nbr[i2] * IN_CH + c] : 0.f;
            fv3 = (i3 < nch) ? feats[st_nbr[i3] * IN_CH + c] : 0.f;
        }
        for (int bi = 0; bi < nch; bi += 64) {
            const int ni = bi + 64;
            float nf0 = 0.f, nf1 = 0.f, nf2 = 0.f, nf3 = 0.f;
            if (ni < nch) {
                const int i0 = ni + slot, i1 = ni + slot + 16,
                          i2 = ni + slot + 32, i3 = ni + slot + 48;
                nf0 = (i0 < nch) ? feats[st_nbr[i0] * IN_CH + c] : 0.f;
                nf1 = (i1 < nch) ? feats[st_nbr[i1] * IN_CH + c] : 0.f;
                nf2 = (i2 < nch) ? feats[st_nbr[i2] * IN_CH + c] : 0.f;
                nf3 = (i3 < nch) ? feats[st_nbr[i3] * IN_CH + c] : 0.f;
            }
            SCAT(bi + slot,      fv0)
            SCAT(bi + slot + 16, fv1)
            SCAT(bi + slot + 32, fv2)
            SCAT(bi + slot + 48, fv3)
            fv0 = nf0; fv1 = nf1; fv2 = nf2; fv3 = nf3;
        }
        #undef SCAT
        __syncthreads();
    }

    // ------- Phase B (sparse, W double-buffered): y[g][o] = sum_k A[g][k][:] . W[k][:][o]
    const int wave = tid >> 6;   // g
    const int o4   = lane & 15;
    const int i4   = lane >> 4;

    const unsigned int mlo = __builtin_amdgcn_readfirstlane(mask_s[wave][0]);
    const unsigned int mhi = __builtin_amdgcn_readfirstlane(mask_s[wave][1]);
    unsigned long long m = ((unsigned long long)mhi << 32) | mlo;

    float4 acc0 = make_float4(0.f, 0.f, 0.f, 0.f);
    float4 acc1 = make_float4(0.f, 0.f, 0.f, 0.f);
    float4 acc2 = make_float4(0.f, 0.f, 0.f, 0.f);
    float4 acc3 = make_float4(0.f, 0.f, 0.f, 0.f);

    const float4* __restrict__ W4 = (const float4*)Wmat;
    const float*  __restrict__ Ag = &A_s[(wave * K3) * IN_CH];

    float4 wA[8];   // all indices below are literals -> registers
    float4 wB[8];

    #define LOADW(P, K) { const float4* Wk = &W4[(((K) << 5) + (i4 << 3)) * 16 + o4]; \
        P[0] = Wk[0];  P[1] = Wk[16]; P[2] = Wk[32]; P[3] = Wk[48];                    \
        P[4] = Wk[64]; P[5] = Wk[80]; P[6] = Wk[96]; P[7] = Wk[112]; }

    #define DOFMA(P, K) {                                                     \
        const float4 a0 = *(const float4*)&Ag[((K) << 5) + (i4 << 3)];        \
        const float4 a1 = *(const float4*)&Ag[((K) << 5) + (i4 << 3) + 4];    \
        acc0.x = fmaf(a0.x, P[0].x, acc0.x); acc0.y = fmaf(a0.x, P[0].y, acc0.y); \
        acc0.z = fmaf(a0.x, P[0].z, acc0.z); acc0.w = fmaf(a0.x, P[0].w, acc0.w); \
        acc1.x = fmaf(a0.y, P[1].x, acc1.x); acc1.y = fmaf(a0.y, P[1].y, acc1.y); \
        acc1.z = fmaf(a0.y, P[1].z, acc1.z); acc1.w = fmaf(a0.y, P[1].w, acc1.w); \
        acc2.x = fmaf(a0.z, P[2].x, acc2.x); acc2.y = fmaf(a0.z, P[2].y, acc2.y); \
        acc2.z = fmaf(a0.z, P[2].z, acc2.z); acc2.w = fmaf(a0.z, P[2].w, acc2.w); \
        acc3.x = fmaf(a0.w, P[3].x, acc3.x); acc3.y = fmaf(a0.w, P[3].y, acc3.y); \
        acc3.z = fmaf(a0.w, P[3].z, acc3.z); acc3.w = fmaf(a0.w, P[3].w, acc3.w); \
        acc0.x = fmaf(a1.x, P[4].x, acc0.x); acc0.y = fmaf(a1.x, P[4].y, acc0.y); \
        acc0.z = fmaf(a1.x, P[4].z, acc0.z); acc0.w = fmaf(a1.x, P[4].w, acc0.w); \
        acc1.x = fmaf(a1.y, P[5].x, acc1.x); acc1.y = fmaf(a1.y, P[5].y, acc1.y); \
        acc1.z = fmaf(a1.y, P[5].z, acc1.z); acc1.w = fmaf(a1.y, P[5].w, acc1.w); \
        acc2.x = fmaf(a1.z, P[6].x, acc2.x); acc2.y = fmaf(a1.z, P[6].y, acc2.y); \
        acc2.z = fmaf(a1.z, P[6].z, acc2.z); acc2.w = fmaf(a1.z, P[6].w, acc2.w); \
        acc3.x = fmaf(a1.w, P[7].x, acc3.x); acc3.y = fmaf(a1.w, P[7].y, acc3.y); \
        acc3.z = fmaf(a1.w, P[7].z, acc3.z); acc3.w = fmaf(a1.w, P[7].w, acc3.w); }

    int kA = -1, kB = -1;
    if (m) { kA = __ffsll(m) - 1; m &= m - 1; LOADW(wA, kA) }
    while (kA >= 0) {
        kB = -1;
        if (m) { kB = __ffsll(m) - 1; m &= m - 1; LOADW(wB, kB) }
        DOFMA(wA, kA)
        if (kB < 0) break;
        kA = -1;
        if (m) { kA = __ffsll(m) - 1; m &= m - 1; LOADW(wA, kA) }
        DOFMA(wB, kB)
    }
    #undef LOADW
    #undef DOFMA

    float4 t;
    t.x = (acc0.x + acc1.x) + (acc2.x + acc3.x);
    t.y = (acc0.y + acc1.y) + (acc2.y + acc3.y);
    t.z = (acc0.z + acc1.z) + (acc2.z + acc3.z);
    t.w = (acc0.w + acc1.w) + (acc2.w + acc3.w);

    // reduce across the 4 i4 groups
    t.x += __shfl_xor(t.x, 16); t.y += __shfl_xor(t.y, 16);
    t.z += __shfl_xor(t.z, 16); t.w += __shfl_xor(t.w, 16);
    t.x += __shfl_xor(t.x, 32); t.y += __shfl_xor(t.y, 32);
    t.z += __shfl_xor(t.z, 32); t.w += __shfl_xor(t.w, 32);

    const int row = g0 + wave;
    if (lane < 16 && row < n_out) {
        float d = den_s[wave];
        d = (d != 0.f) ? d : 1.f;
        const float inv_d = 1.f / d;
        const float4 b4 = ((const float4*)bias)[o4];
        float4 y;
        y.x = fmaxf(t.x * inv_d + b4.x, 0.f);
        y.y = fmaxf(t.y * inv_d + b4.y, 0.f);
        y.z = fmaxf(t.z * inv_d + b4.z, 0.f);
        y.w = fmaxf(t.w * inv_d + b4.w, 0.f);
        ((float4*)out)[row * 16 + o4] = y;
    }
}

extern "C" void kernel_launch(void* const* d_in, const int* in_sizes, int n_in,
                              void* d_out, int out_size, void* d_ws, size_t ws_size,
                              hipStream_t stream) {
    const float* feats        = (const float*)d_in[0];
    const float* inp_points   = (const float*)d_in[1];
    const float* out_points   = (const float*)d_in[2];
    const float* out_extents  = (const float*)d_in[3];
    const float* scale_compat = (const float*)d_in[4];
    const int*   nbr_index    = (const int*)d_in[5];
    const int*   row_splits   = (const int*)d_in[6];
    const float* nbr_dist     = (const float*)d_in[7];
    const float* Wmat         = (const float*)d_in[8];
    const float* bias         = (const float*)d_in[9];
    float*       out          = (float*)d_out;

    const int n_out = in_sizes[2] / 3;
    if (n_out <= 0) return;
    const int nwg = (n_out + G - 1) / G;

    hipLaunchKernelGGL(cconv_fused_kernel, dim3(nwg), dim3(THREADS), 0, stream,
                       feats, inp_points, out_points, out_extents, scale_compat,
                       nbr_index, row_splits, nbr_dist, Wmat, bias, out, n_out);
}